// Round 7
// baseline (573.422 us; speedup 1.0000x reference)
//
#include <hip/hip_runtime.h>
#include <hip/hip_bf16.h>
#include <math.h>

static __device__ __forceinline__ float sigm(float x) { return 1.0f / (1.0f + expf(-x)); }

// fp32 -> bf16 bits, round-to-nearest-even
static __device__ __forceinline__ short f2bf_s(float f) {
    unsigned u = __float_as_uint(f);
    u += 0x7fffu + ((u >> 16) & 1u);
    return (short)(u >> 16);
}
// bf16 bits -> fp32
static __device__ __forceinline__ float bfb2f(short s) {
    return __uint_as_float(((unsigned)(unsigned short)s) << 16);
}

typedef __attribute__((ext_vector_type(8))) short short8;
typedef __attribute__((ext_vector_type(4))) short short4v;
typedef __attribute__((ext_vector_type(4))) float f32x4;

// ---------------- fused map pipeline -> om (bf16) ----------------
__global__ __launch_bounds__(256) void k_maps(const float* __restrict__ in_map,
                                              short* __restrict__ om_bf) {
    __shared__ float s_u[20][20];
    __shared__ float s_inc[18][18];
    int tid = threadIdx.x;
    int b = blockIdx.z;
    int ty0 = (blockIdx.x >> 3) << 4, tx0 = (blockIdx.x & 7) << 4;
    const float* p = in_map + (b << 12);
    const float s = 63.0f / 127.0f;
    for (int e = tid; e < 400; e += 256) {
        int yy = e / 20, xx = e % 20;
        int gy = ty0 + yy - 2, gx = tx0 + xx - 2;
        float v = 0.0f;
        if ((unsigned)gy < 128u && (unsigned)gx < 128u) {
            float cy = gy * s, cx = gx * s;
            int iy0 = (int)cy, ix0 = (int)cx;
            float wy = cy - (float)iy0, wx = cx - (float)ix0;
            int iy1 = min(iy0 + 1, 63), ix1 = min(ix0 + 1, 63);
            float v00 = p[(iy0 << 6) + ix0], v01 = p[(iy0 << 6) + ix1];
            float v10 = p[(iy1 << 6) + ix0], v11 = p[(iy1 << 6) + ix1];
            v = (1.0f - wy) * ((1.0f - wx) * v00 + wx * v01) +
                wy          * ((1.0f - wx) * v10 + wx * v11);
        }
        s_u[yy][xx] = v;
    }
    __syncthreads();
    for (int e = tid; e < 324; e += 256) {
        int yy = e / 18, xx = e % 18;
        int gy = ty0 + yy - 1, gx = tx0 + xx - 1;
        float val = -INFINITY;
        if ((unsigned)gy < 128u && (unsigned)gx < 128u) {
            float uc = s_u[yy + 1][xx + 1];
            float mx = -INFINITY;
            for (int dy = -1; dy <= 1; ++dy) {
                int ny = gy + dy; if ((unsigned)ny >= 128u) continue;
                for (int dx = -1; dx <= 1; ++dx) {
                    int nx = gx + dx; if ((unsigned)nx >= 128u) continue;
                    mx = fmaxf(mx, s_u[yy + 1 + dy][xx + 1 + dx]);
                }
            }
            val = sigm(mx) - sigm(uc);
        }
        s_inc[yy][xx] = val;
    }
    __syncthreads();
    int row = tid >> 4, col = tid & 15;
    int gy = ty0 + row, gx = tx0 + col;
    float mx = -INFINITY;
    #pragma unroll
    for (int dy = 0; dy < 3; ++dy)
        #pragma unroll
        for (int dx = 0; dx < 3; ++dx)
            mx = fmaxf(mx, s_inc[row + dy][col + dx]);
    float uc = s_u[row + 2][col + 2];
    float mn = INFINITY;
    for (int dy = -1; dy <= 1; ++dy) {
        int ny = gy + dy; if ((unsigned)ny >= 128u) continue;
        for (int dx = -1; dx <= 1; ++dx) {
            int nx = gx + dx; if ((unsigned)nx >= 128u) continue;
            mn = fminf(mn, s_u[row + 2 + dy][col + 2 + dx]);
        }
    }
    float inc2 = sigm(1.0f - mn) - sigm(1.0f - uc);
    om_bf[(b << 14) + (gy << 7) + gx] = f2bf_s(mx + inc2);
}

// ---------------- premultiply: xin2 = bf16(om * cur_x) ----------------
__global__ __launch_bounds__(256) void k_premult(const float* __restrict__ cur_x,
                                                 const short* __restrict__ om_bf,
                                                 short* __restrict__ xin2) {
    int e = blockIdx.x * 256 + threadIdx.x;
    int flat = e << 2;
    int pix = flat & 16383;
    int b = flat >> 20;
    f32x4 xv = *(const f32x4*)&cur_x[flat];
    short4v ov = *(const short4v*)&om_bf[(b << 14) + pix];
    short4v res;
    #pragma unroll
    for (int k = 0; k < 4; ++k) res[k] = f2bf_s(xv[k] * bfb2f(ov[k]));
    *(short4v*)&xin2[flat] = res;
}

// ---------------- conv3 weight prep ----------------
__global__ __launch_bounds__(256) void k_prepw3(const float* __restrict__ w0,
                                                const float* __restrict__ w1,
                                                const float* __restrict__ w2,
                                                const float* __restrict__ w3,
                                                short* __restrict__ wb3) {
    int s = blockIdx.x * 256 + threadIdx.x;
    if (s >= 147456) return;
    int layer = s / 36864; int r = s - layer * 36864;
    const float* w = (layer == 0) ? w0 : (layer == 1) ? w1 : (layer == 2) ? w2 : w3;
    int o = r / 576; int rem = r - o * 576;
    int c = rem / 9; int t = rem - c * 9;
    int dy = t / 3, dx = t - dy * 3;
    int cc = c >> 5, cl = c & 31;
    wb3[layer * 36864 + (((cc * 3 + dy) * 3 + dx) * 64 + o) * 32 + cl] = f2bf_s(w[r]);
}

// ---------------- upconv weight prep ----------------
__global__ __launch_bounds__(256) void k_prepw(const float* __restrict__ w,
                                               short* __restrict__ wb) {
    int s = blockIdx.x * 256 + threadIdx.x;
    if (s >= 1605632) return;
    int O = s / 6272; int r = s - O * 6272;
    int C = r / 49;   int T = r - C * 49;
    int dy = T / 7, dx = T - dy * 7;
    int nt = O >> 6, o = O & 63;
    int cc = C >> 5, c = C & 31;
    int W = ((((nt * 4 + cc) * 7 + dy) * 7 + dx) * 64 + o) * 32 + c;
    wb[W] = f2bf_s(w[s]);
}

// ---------------- up-conv 7x7 MFMA v4: 8-row tiles (4 blk/CU), aligned f32x4 staging ----------------
// Block: 4 waves, tile 8x16 px (wave = 2 rows), all 64 oc of nt (j=0..3).
// A via LDS stride-40 (verified); B frags direct global (L1/L2-hit).
__global__ __launch_bounds__(256) void k_upconv_mfma(
    const float* __restrict__ x,      // [8,128,64,64]
    const short* __restrict__ wb,     // prepped [nt4][cc4][dy7][dx7][o64][c32]
    const float* __restrict__ cb,     // [256]
    const float* __restrict__ bnp,    // [4,256]
    short* __restrict__ dep) {        // [8,64,128,128] bf16
    __shared__ __attribute__((aligned(16))) short s_in[308 * 40];  // 14x22 cells
    int tid = threadIdx.x;
    int mw = tid >> 6, lane = tid & 63;
    int q = lane >> 4, m = lane & 15;
    int ty0 = (blockIdx.x >> 2) * 8;      // 8 y-tiles of 8 rows
    int tx0 = (blockIdx.x & 3) * 16;      // 4 x-tiles of 16 cols
    int nt = blockIdx.y;
    int b = blockIdx.z;
    f32x4 acc[2][4];
    #pragma unroll
    for (int i = 0; i < 2; ++i)
        #pragma unroll
        for (int j = 0; j < 4; ++j)
            acc[i][j] = (f32x4){0.f, 0.f, 0.f, 0.f};
    const float* xb = x + ((long)(b * 128) << 12);
    for (int cc = 0; cc < 4; ++cc) {
        __syncthreads();   // previous-iter readers of s_in done
        // staging: groups of 4 x at gx0 % 4 == 0 (width 64 => group all-in or all-out)
        for (int e = tid; e < 336; e += 256) {
            int cq = e / 84; int rem = e - cq * 84;
            int yy = rem / 6; int g = rem - yy * 6;
            int gy = ty0 + yy - 3;
            int gx0 = tx0 - 4 + (g << 2);
            f32x4 v[8];
            if ((unsigned)gy < 64u && (unsigned)gx0 < 64u) {
                const float* src = xb + ((cc * 32 + cq * 8) << 12) + (gy << 6) + gx0;
                #pragma unroll
                for (int j2 = 0; j2 < 8; ++j2) v[j2] = *(const f32x4*)(src + (j2 << 12));
            } else {
                #pragma unroll
                for (int j2 = 0; j2 < 8; ++j2) v[j2] = (f32x4){0.f, 0.f, 0.f, 0.f};
            }
            #pragma unroll
            for (int t = 0; t < 4; ++t) {
                int xx = (g << 2) - 1 + t;
                if ((unsigned)xx < 22u) {
                    short8 pk;
                    #pragma unroll
                    for (int j2 = 0; j2 < 8; ++j2) pk[j2] = f2bf_s(v[j2][t]);
                    *(short8*)&s_in[(yy * 22 + xx) * 40 + cq * 8] = pk;
                }
            }
        }
        __syncthreads();
        for (int dy = 0; dy < 7; ++dy) {
            const short* wsl = wb + (((nt * 4 + cc) * 7 + dy) * 7) * 2048;
            #pragma unroll
            for (int dx = 0; dx < 7; ++dx) {
                short8 bf[4];
                #pragma unroll
                for (int j = 0; j < 4; ++j)
                    bf[j] = *(const short8*)(wsl + (dx << 11) + ((j * 16 + m) << 5) + (q << 3));
                short8 a[2];
                #pragma unroll
                for (int i = 0; i < 2; ++i)
                    a[i] = *(const short8*)&s_in[((mw * 2 + i + dy) * 22 + m + dx) * 40 + q * 8];
                #pragma unroll
                for (int i = 0; i < 2; ++i)
                    #pragma unroll
                    for (int j = 0; j < 4; ++j)
                        acc[i][j] = __builtin_amdgcn_mfma_f32_16x16x32_bf16(
                            a[i], bf[j], acc[i][j], 0, 0, 0);
            }
        }
    }
    // epilogue: bias + BN + ReLU + pixel-shuffle scatter (bf16)
    #pragma unroll
    for (int j = 0; j < 4; ++j) {
        int o = nt * 64 + j * 16 + m;
        float g  = bnp[o],       bt = bnp[256 + o];
        float mn = bnp[512 + o], vv = bnp[768 + o];
        float scale = g * rsqrtf(vv + 1e-5f);
        float cbf = cb[o];
        int c = o >> 2, sbit = (o >> 1) & 1, tbit = o & 1;
        #pragma unroll
        for (int i = 0; i < 2; ++i) {
            int y = ty0 + mw * 2 + i;
            #pragma unroll
            for (int reg = 0; reg < 4; ++reg) {
                int xc = tx0 + q * 4 + reg;
                float val = (acc[i][j][reg] + cbf - mn) * scale + bt;
                val = fmaxf(val, 0.0f);
                dep[((b * 64 + c) << 14) + ((2 * y + sbit) << 7) + (2 * xc + tbit)] = f2bf_s(val);
            }
        }
    }
}

// ---------------- 3x3 conv 64->64 via MFMA, aligned short4 staging ----------------
template <int MODE, bool OUTBF>
__global__ __launch_bounds__(256) void k_conv3m(
    const short* __restrict__ xin,
    const short* __restrict__ wl,
    const short* __restrict__ dep,
    const float* __restrict__ cb,
    const float* __restrict__ bnp,
    const float* __restrict__ beta,
    void* __restrict__ out) {
    __shared__ __attribute__((aligned(16))) short s_in[180 * 40];
    int tid = threadIdx.x;
    int wave = tid >> 6, lane = tid & 63;
    int q = lane >> 4, m = lane & 15;
    int mw = wave >> 1, nw = wave & 1;
    int ty0 = (blockIdx.x >> 3) * 8;
    int tx0 = (blockIdx.x & 7) * 16;
    int b = blockIdx.z;
    f32x4 acc[4][2];
    #pragma unroll
    for (int i = 0; i < 4; ++i)
        #pragma unroll
        for (int j = 0; j < 2; ++j)
            acc[i][j] = (f32x4){0.f, 0.f, 0.f, 0.f};
    const short* xb = xin + ((long)(b * 64) << 14);
    for (int cc = 0; cc < 2; ++cc) {
        __syncthreads();
        // staging: groups of 4 x at gx0 % 4 == 0 (width 128 => group all-in or all-out)
        for (int e = tid; e < 240; e += 256) {
            int cq = e / 60; int rem = e - cq * 60;
            int yy = rem / 6; int g = rem - yy * 6;
            int gy = ty0 + yy - 1;
            int gx0 = tx0 - 4 + (g << 2);
            short4v v[8];
            if ((unsigned)gy < 128u && (unsigned)gx0 < 128u) {
                const short* src = xb + ((cc * 32 + cq * 8) << 14) + (gy << 7) + gx0;
                #pragma unroll
                for (int j2 = 0; j2 < 8; ++j2) v[j2] = *(const short4v*)(src + (j2 << 14));
            } else {
                #pragma unroll
                for (int j2 = 0; j2 < 8; ++j2) v[j2] = (short4v){0, 0, 0, 0};
            }
            #pragma unroll
            for (int t = 0; t < 4; ++t) {
                int xx = (g << 2) - 3 + t;
                if ((unsigned)xx < 18u) {
                    short8 pk;
                    #pragma unroll
                    for (int j2 = 0; j2 < 8; ++j2) pk[j2] = v[j2][t];
                    *(short8*)&s_in[(yy * 18 + xx) * 40 + cq * 8] = pk;
                }
            }
        }
        __syncthreads();
        #pragma unroll
        for (int dy = 0; dy < 3; ++dy) {
            #pragma unroll
            for (int dx = 0; dx < 3; ++dx) {
                const short* wp = wl + (((cc * 3 + dy) * 3 + dx) << 11);
                short8 bf[2];
                #pragma unroll
                for (int j = 0; j < 2; ++j)
                    bf[j] = *(const short8*)(wp + ((nw * 32 + j * 16 + m) << 5) + (q << 3));
                short8 a[4];
                #pragma unroll
                for (int i = 0; i < 4; ++i)
                    a[i] = *(const short8*)&s_in[((mw * 4 + i + dy) * 18 + m + dx) * 40 + q * 8];
                #pragma unroll
                for (int i = 0; i < 4; ++i)
                    #pragma unroll
                    for (int j = 0; j < 2; ++j)
                        acc[i][j] = __builtin_amdgcn_mfma_f32_16x16x32_bf16(
                            a[i], bf[j], acc[i][j], 0, 0, 0);
            }
        }
    }
    float betav = (MODE == 1) ? beta[0] : 0.0f;
    #pragma unroll
    for (int j = 0; j < 2; ++j) {
        int o = nw * 32 + j * 16 + m;
        float cbf = cb[o];
        float scale = 1.0f, shift = 0.0f;
        if (MODE == 0) {
            float g  = bnp[o],       bt = bnp[64 + o];
            float mm = bnp[128 + o], vv = bnp[192 + o];
            scale = g * rsqrtf(vv + 1e-5f);
            shift = bt - mm * scale;
        }
        #pragma unroll
        for (int i = 0; i < 4; ++i) {
            int y = ty0 + mw * 4 + i;
            int base = ((b * 64 + o) << 14) + (y << 7) + tx0 + q * 4;
            float vals[4];
            if (MODE == 1) {
                short4v dv = *(const short4v*)&dep[base];
                #pragma unroll
                for (int reg = 0; reg < 4; ++reg)
                    vals[reg] = bfb2f(dv[reg]) + betav * (acc[i][j][reg] + cbf);
            } else {
                #pragma unroll
                for (int reg = 0; reg < 4; ++reg)
                    vals[reg] = fmaxf((acc[i][j][reg] + cbf) * scale + shift, 0.0f);
            }
            if (OUTBF) {
                short4v sv;
                #pragma unroll
                for (int reg = 0; reg < 4; ++reg) sv[reg] = f2bf_s(vals[reg]);
                *(short4v*)((short*)out + base) = sv;
            } else {
                f32x4 fv;
                #pragma unroll
                for (int reg = 0; reg < 4; ++reg) fv[reg] = vals[reg];
                *(f32x4*)((float*)out + base) = fv;
            }
        }
    }
}

// ---------------- final 7x7 conv (64->1), fp32 (unchanged) ----------------
__global__ __launch_bounds__(256) void k_outconv(
    const float* __restrict__ r,
    const float* __restrict__ w,
    const float* __restrict__ ob,
    float* __restrict__ out) {
    __shared__ float s_in[8][22][22];
    __shared__ float s_w[64 * 49];
    int tid = threadIdx.x;
    int ty = tid >> 4, tx = tid & 15;
    int ty0 = (blockIdx.x >> 3) << 4, tx0 = (blockIdx.x & 7) << 4;
    int b = blockIdx.z;
    for (int e = tid; e < 64 * 49; e += 256) s_w[e] = w[e];
    float acc = 0.0f;
    for (int c0 = 0; c0 < 64; c0 += 8) {
        __syncthreads();
        for (int e = tid; e < 8 * 484; e += 256) {
            int i = e / 484; int r2 = e - i * 484; int yy = r2 / 22; int xx = r2 - yy * 22;
            int gy = ty0 + yy - 3, gx = tx0 + xx - 3;
            float v = 0.0f;
            if ((unsigned)gy < 128u && (unsigned)gx < 128u)
                v = r[((b * 64 + c0 + i) << 14) + (gy << 7) + gx];
            s_in[i][yy][xx] = v;
        }
        __syncthreads();
        for (int i = 0; i < 8; ++i) {
            #pragma unroll
            for (int dy = 0; dy < 7; ++dy)
                #pragma unroll
                for (int dx = 0; dx < 7; ++dx)
                    acc = fmaf(s_in[i][ty + dy][tx + dx], s_w[(c0 + i) * 49 + dy * 7 + dx], acc);
        }
    }
    out[(b << 14) + ((ty0 + ty) << 7) + tx0 + tx] = acc + ob[0];
}

extern "C" void kernel_launch(void* const* d_in, const int* in_sizes, int n_in,
                              void* d_out, int out_size, void* d_ws, size_t ws_size,
                              hipStream_t stream) {
    const float* cur_x  = (const float*)d_in[0];
    const float* dep_x  = (const float*)d_in[1];
    const float* in_map = (const float*)d_in[2];
    const float* up_w   = (const float*)d_in[3];
    const float* up_b   = (const float*)d_in[4];
    const float* up_bn  = (const float*)d_in[5];
    const float* c2_w   = (const float*)d_in[6];
    const float* c2_b   = (const float*)d_in[7];
    const float* d1_w   = (const float*)d_in[8];
    const float* d1_b   = (const float*)d_in[9];
    const float* d1_bn  = (const float*)d_in[10];
    const float* d2_w   = (const float*)d_in[11];
    const float* d2_b   = (const float*)d_in[12];
    const float* d2_bn  = (const float*)d_in[13];
    const float* d3_w   = (const float*)d_in[14];
    const float* d3_b   = (const float*)d_in[15];
    const float* d3_bn  = (const float*)d_in[16];
    const float* out_w  = (const float*)d_in[17];
    const float* out_b  = (const float*)d_in[18];
    const float* beta   = (const float*)d_in[19];

    // Buffer plan (ws use = 16.8 MiB, proven safe):
    //   A  = ws[0..16.8M) bf16      : xin2 (steps 2-6) then r2 (steps 8-9)
    //   B  = d_out[0..16.8M) bf16   : dep (5-6) then r1 (7-8)
    //   C  = d_out[16.8..33.5M) bf16: wb at head (4-5) then t (6-7)
    //   map region d_out[33.5..34M) : om_bf (1-2) -> wb3 (3-9) -> final map (10)
    //   r_out fp32 = d_out[0..33.5M): final r written by d3 (step 9)
    char* ob = (char*)d_out;
    float* r_out  = (float*)ob;
    short* A      = (short*)d_ws;
    short* B      = (short*)ob;
    short* C      = (short*)(ob + 16777216);
    short* wb     = C;
    short* om_bf  = (short*)(ob + 33554432);
    short* wb3    = (short*)(ob + 33554432);
    float* mapout = (float*)(ob + 33554432);

    k_maps<<<dim3(64, 1, 8), 256, 0, stream>>>(in_map, om_bf);
    k_premult<<<8192, 256, 0, stream>>>(cur_x, om_bf, A);
    k_prepw3<<<576, 256, 0, stream>>>(c2_w, d1_w, d2_w, d3_w, wb3);
    k_prepw<<<6272, 256, 0, stream>>>(up_w, wb);
    k_upconv_mfma<<<dim3(32, 4, 8), 256, 0, stream>>>(dep_x, wb, up_b, up_bn, B);
    k_conv3m<1, true><<<dim3(128, 1, 8), 256, 0, stream>>>(
        A, wb3 + 0 * 36864, B, c2_b, nullptr, beta, C);
    k_conv3m<0, true><<<dim3(128, 1, 8), 256, 0, stream>>>(
        C, wb3 + 1 * 36864, nullptr, d1_b, d1_bn, nullptr, B);
    k_conv3m<0, true><<<dim3(128, 1, 8), 256, 0, stream>>>(
        B, wb3 + 2 * 36864, nullptr, d2_b, d2_bn, nullptr, A);
    k_conv3m<0, false><<<dim3(128, 1, 8), 256, 0, stream>>>(
        A, wb3 + 3 * 36864, nullptr, d3_b, d3_bn, nullptr, r_out);
    k_outconv<<<dim3(64, 1, 8), 256, 0, stream>>>(r_out, out_w, out_b, mapout);
}

// Round 8
// 467.394 us; speedup vs baseline: 1.2269x; 1.2269x over previous
//
#include <hip/hip_runtime.h>
#include <hip/hip_bf16.h>
#include <math.h>

static __device__ __forceinline__ float sigm(float x) { return 1.0f / (1.0f + expf(-x)); }

// fp32 -> bf16 bits, round-to-nearest-even
static __device__ __forceinline__ short f2bf_s(float f) {
    unsigned u = __float_as_uint(f);
    u += 0x7fffu + ((u >> 16) & 1u);
    return (short)(u >> 16);
}
// bf16 bits -> fp32
static __device__ __forceinline__ float bfb2f(short s) {
    return __uint_as_float(((unsigned)(unsigned short)s) << 16);
}

typedef __attribute__((ext_vector_type(8))) short short8;
typedef __attribute__((ext_vector_type(4))) short short4v;
typedef __attribute__((ext_vector_type(4))) float f32x4;

// ---------------- fused map pipeline -> om (bf16) ----------------
__global__ __launch_bounds__(256) void k_maps(const float* __restrict__ in_map,
                                              short* __restrict__ om_bf) {
    __shared__ float s_u[20][20];
    __shared__ float s_inc[18][18];
    int tid = threadIdx.x;
    int b = blockIdx.z;
    int ty0 = (blockIdx.x >> 3) << 4, tx0 = (blockIdx.x & 7) << 4;
    const float* p = in_map + (b << 12);
    const float s = 63.0f / 127.0f;
    for (int e = tid; e < 400; e += 256) {
        int yy = e / 20, xx = e % 20;
        int gy = ty0 + yy - 2, gx = tx0 + xx - 2;
        float v = 0.0f;
        if ((unsigned)gy < 128u && (unsigned)gx < 128u) {
            float cy = gy * s, cx = gx * s;
            int iy0 = (int)cy, ix0 = (int)cx;
            float wy = cy - (float)iy0, wx = cx - (float)ix0;
            int iy1 = min(iy0 + 1, 63), ix1 = min(ix0 + 1, 63);
            float v00 = p[(iy0 << 6) + ix0], v01 = p[(iy0 << 6) + ix1];
            float v10 = p[(iy1 << 6) + ix0], v11 = p[(iy1 << 6) + ix1];
            v = (1.0f - wy) * ((1.0f - wx) * v00 + wx * v01) +
                wy          * ((1.0f - wx) * v10 + wx * v11);
        }
        s_u[yy][xx] = v;
    }
    __syncthreads();
    for (int e = tid; e < 324; e += 256) {
        int yy = e / 18, xx = e % 18;
        int gy = ty0 + yy - 1, gx = tx0 + xx - 1;
        float val = -INFINITY;
        if ((unsigned)gy < 128u && (unsigned)gx < 128u) {
            float uc = s_u[yy + 1][xx + 1];
            float mx = -INFINITY;
            for (int dy = -1; dy <= 1; ++dy) {
                int ny = gy + dy; if ((unsigned)ny >= 128u) continue;
                for (int dx = -1; dx <= 1; ++dx) {
                    int nx = gx + dx; if ((unsigned)nx >= 128u) continue;
                    mx = fmaxf(mx, s_u[yy + 1 + dy][xx + 1 + dx]);
                }
            }
            val = sigm(mx) - sigm(uc);
        }
        s_inc[yy][xx] = val;
    }
    __syncthreads();
    int row = tid >> 4, col = tid & 15;
    int gy = ty0 + row, gx = tx0 + col;
    float mx = -INFINITY;
    #pragma unroll
    for (int dy = 0; dy < 3; ++dy)
        #pragma unroll
        for (int dx = 0; dx < 3; ++dx)
            mx = fmaxf(mx, s_inc[row + dy][col + dx]);
    float uc = s_u[row + 2][col + 2];
    float mn = INFINITY;
    for (int dy = -1; dy <= 1; ++dy) {
        int ny = gy + dy; if ((unsigned)ny >= 128u) continue;
        for (int dx = -1; dx <= 1; ++dx) {
            int nx = gx + dx; if ((unsigned)nx >= 128u) continue;
            mn = fminf(mn, s_u[row + 2 + dy][col + 2 + dx]);
        }
    }
    float inc2 = sigm(1.0f - mn) - sigm(1.0f - uc);
    om_bf[(b << 14) + (gy << 7) + gx] = f2bf_s(mx + inc2);
}

// ---------------- premultiply: xin2 = bf16(om * cur_x) ----------------
__global__ __launch_bounds__(256) void k_premult(const float* __restrict__ cur_x,
                                                 const short* __restrict__ om_bf,
                                                 short* __restrict__ xin2) {
    int e = blockIdx.x * 256 + threadIdx.x;
    int flat = e << 2;
    int pix = flat & 16383;
    int b = flat >> 20;
    f32x4 xv = *(const f32x4*)&cur_x[flat];
    short4v ov = *(const short4v*)&om_bf[(b << 14) + pix];
    short4v res;
    #pragma unroll
    for (int k = 0; k < 4; ++k) res[k] = f2bf_s(xv[k] * bfb2f(ov[k]));
    *(short4v*)&xin2[flat] = res;
}

// ---------------- conv3 weight prep ----------------
__global__ __launch_bounds__(256) void k_prepw3(const float* __restrict__ w0,
                                                const float* __restrict__ w1,
                                                const float* __restrict__ w2,
                                                const float* __restrict__ w3,
                                                short* __restrict__ wb3) {
    int s = blockIdx.x * 256 + threadIdx.x;
    if (s >= 147456) return;
    int layer = s / 36864; int r = s - layer * 36864;
    const float* w = (layer == 0) ? w0 : (layer == 1) ? w1 : (layer == 2) ? w2 : w3;
    int o = r / 576; int rem = r - o * 576;
    int c = rem / 9; int t = rem - c * 9;
    int dy = t / 3, dx = t - dy * 3;
    int cc = c >> 5, cl = c & 31;
    wb3[layer * 36864 + (((cc * 3 + dy) * 3 + dx) * 64 + o) * 32 + cl] = f2bf_s(w[r]);
}

// ---------------- upconv weight prep ----------------
__global__ __launch_bounds__(256) void k_prepw(const float* __restrict__ w,
                                               short* __restrict__ wb) {
    int s = blockIdx.x * 256 + threadIdx.x;
    if (s >= 1605632) return;
    int O = s / 6272; int r = s - O * 6272;
    int C = r / 49;   int T = r - C * 49;
    int dy = T / 7, dx = T - dy * 7;
    int nt = O >> 6, o = O & 63;
    int cc = C >> 5, c = C & 31;
    int W = ((((nt * 4 + cc) * 7 + dy) * 7 + dx) * 64 + o) * 32 + c;
    wb[W] = f2bf_s(w[s]);
}

// ---------------- up-conv 7x7 MFMA v5: 16x16 tile, 8-wave blocks (oc split) ----------------
// Block: 512 thr = 8 waves; mw = wave&3 (rows), ng = wave>>2 (oc half).
// Per-block B traffic identical to v3 (16 frag-loads / 64 MFMA per step); 16 waves/CU.
__global__ __launch_bounds__(512) void k_upconv_mfma(
    const float* __restrict__ x,      // [8,128,64,64]
    const short* __restrict__ wb,     // prepped [nt4][cc4][dy7][dx7][o64][c32]
    const float* __restrict__ cb,     // [256]
    const float* __restrict__ bnp,    // [4,256]
    short* __restrict__ dep) {        // [8,64,128,128] bf16
    __shared__ __attribute__((aligned(16))) short s_in[484 * 40];  // 22x22 cells
    int tid = threadIdx.x;
    int wave = tid >> 6, lane = tid & 63;
    int q = lane >> 4, m = lane & 15;
    int mw = wave & 3, ng = wave >> 2;
    int ty0 = (blockIdx.x >> 2) * 16;     // 4 y-tiles of 16 rows
    int tx0 = (blockIdx.x & 3) * 16;      // 4 x-tiles of 16 cols
    int nt = blockIdx.y;
    int b = blockIdx.z;
    f32x4 acc[4][2];
    #pragma unroll
    for (int i = 0; i < 4; ++i)
        #pragma unroll
        for (int j = 0; j < 2; ++j)
            acc[i][j] = (f32x4){0.f, 0.f, 0.f, 0.f};
    const float* xb = x + ((long)(b * 128) << 12);
    for (int cc = 0; cc < 4; ++cc) {
        __syncthreads();   // previous-iter readers of s_in done
        // staging: aligned groups of 4 x (width 64 => group all-in or all-out)
        for (int e = tid; e < 528; e += 512) {
            int cq = e / 132; int rem = e - cq * 132;
            int yy = rem / 6; int g = rem - yy * 6;
            int gy = ty0 + yy - 3;
            int gx0 = tx0 - 4 + (g << 2);
            bool ok = ((unsigned)gy < 64u) && ((unsigned)gx0 < 64u);
            #pragma unroll
            for (int h = 0; h < 2; ++h) {
                f32x4 v[4];
                if (ok) {
                    const float* src = xb + ((cc * 32 + cq * 8 + h * 4) << 12) + (gy << 6) + gx0;
                    #pragma unroll
                    for (int j2 = 0; j2 < 4; ++j2) v[j2] = *(const f32x4*)(src + (j2 << 12));
                } else {
                    #pragma unroll
                    for (int j2 = 0; j2 < 4; ++j2) v[j2] = (f32x4){0.f, 0.f, 0.f, 0.f};
                }
                #pragma unroll
                for (int t = 0; t < 4; ++t) {
                    int xx = (g << 2) - 1 + t;
                    if ((unsigned)xx < 22u) {
                        short4v pk;
                        #pragma unroll
                        for (int j2 = 0; j2 < 4; ++j2) pk[j2] = f2bf_s(v[j2][t]);
                        *(short4v*)&s_in[(yy * 22 + xx) * 40 + cq * 8 + h * 4] = pk;
                    }
                }
            }
        }
        __syncthreads();
        for (int dy = 0; dy < 7; ++dy) {
            const short* wsl = wb + (((nt * 4 + cc) * 7 + dy) * 7) * 2048;
            #pragma unroll
            for (int dx = 0; dx < 7; ++dx) {
                short8 bf[2];
                #pragma unroll
                for (int j = 0; j < 2; ++j)
                    bf[j] = *(const short8*)(wsl + (dx << 11) + ((ng * 32 + j * 16 + m) << 5) + (q << 3));
                short8 a[4];
                #pragma unroll
                for (int i = 0; i < 4; ++i)
                    a[i] = *(const short8*)&s_in[((mw * 4 + i + dy) * 22 + m + dx) * 40 + q * 8];
                #pragma unroll
                for (int i = 0; i < 4; ++i)
                    #pragma unroll
                    for (int j = 0; j < 2; ++j)
                        acc[i][j] = __builtin_amdgcn_mfma_f32_16x16x32_bf16(
                            a[i], bf[j], acc[i][j], 0, 0, 0);
            }
        }
    }
    // epilogue: bias + BN + ReLU + pixel-shuffle scatter (bf16)
    #pragma unroll
    for (int j = 0; j < 2; ++j) {
        int o = nt * 64 + ng * 32 + j * 16 + m;
        float g  = bnp[o],       bt = bnp[256 + o];
        float mn = bnp[512 + o], vv = bnp[768 + o];
        float scale = g * rsqrtf(vv + 1e-5f);
        float cbf = cb[o];
        int c = o >> 2, sbit = (o >> 1) & 1, tbit = o & 1;
        #pragma unroll
        for (int i = 0; i < 4; ++i) {
            int y = ty0 + mw * 4 + i;
            #pragma unroll
            for (int reg = 0; reg < 4; ++reg) {
                int xc = tx0 + q * 4 + reg;
                float val = (acc[i][j][reg] + cbf - mn) * scale + bt;
                val = fmaxf(val, 0.0f);
                dep[((b * 64 + c) << 14) + ((2 * y + sbit) << 7) + (2 * xc + tbit)] = f2bf_s(val);
            }
        }
    }
}

// ---------------- 3x3 conv 64->64 via MFMA (unchanged from round 6) ----------------
template <int MODE, bool OUTBF>
__global__ __launch_bounds__(256) void k_conv3m(
    const short* __restrict__ xin,
    const short* __restrict__ wl,
    const short* __restrict__ dep,
    const float* __restrict__ cb,
    const float* __restrict__ bnp,
    const float* __restrict__ beta,
    void* __restrict__ out) {
    __shared__ __attribute__((aligned(16))) short s_in[180 * 40];
    int tid = threadIdx.x;
    int wave = tid >> 6, lane = tid & 63;
    int q = lane >> 4, m = lane & 15;
    int mw = wave >> 1, nw = wave & 1;
    int ty0 = (blockIdx.x >> 3) * 8;
    int tx0 = (blockIdx.x & 7) * 16;
    int b = blockIdx.z;
    f32x4 acc[4][2];
    #pragma unroll
    for (int i = 0; i < 4; ++i)
        #pragma unroll
        for (int j = 0; j < 2; ++j)
            acc[i][j] = (f32x4){0.f, 0.f, 0.f, 0.f};
    const short* xb = xin + ((long)(b * 64) << 14);
    for (int cc = 0; cc < 2; ++cc) {
        __syncthreads();
        for (int e = tid; e < 240; e += 256) {
            int cq = e / 60; int rem = e - cq * 60;
            int yy = rem / 6; int g = rem - yy * 6;
            int gy = ty0 + yy - 1;
            int gx0 = tx0 - 4 + (g << 2);
            short4v v[8];
            if ((unsigned)gy < 128u && (unsigned)gx0 < 128u) {
                const short* src = xb + ((cc * 32 + cq * 8) << 14) + (gy << 7) + gx0;
                #pragma unroll
                for (int j2 = 0; j2 < 8; ++j2) v[j2] = *(const short4v*)(src + (j2 << 14));
            } else {
                #pragma unroll
                for (int j2 = 0; j2 < 8; ++j2) v[j2] = (short4v){0, 0, 0, 0};
            }
            #pragma unroll
            for (int t = 0; t < 4; ++t) {
                int xx = (g << 2) - 3 + t;
                if ((unsigned)xx < 18u) {
                    short8 pk;
                    #pragma unroll
                    for (int j2 = 0; j2 < 8; ++j2) pk[j2] = v[j2][t];
                    *(short8*)&s_in[(yy * 18 + xx) * 40 + cq * 8] = pk;
                }
            }
        }
        __syncthreads();
        #pragma unroll
        for (int dy = 0; dy < 3; ++dy) {
            #pragma unroll
            for (int dx = 0; dx < 3; ++dx) {
                const short* wp = wl + (((cc * 3 + dy) * 3 + dx) << 11);
                short8 bf[2];
                #pragma unroll
                for (int j = 0; j < 2; ++j)
                    bf[j] = *(const short8*)(wp + ((nw * 32 + j * 16 + m) << 5) + (q << 3));
                short8 a[4];
                #pragma unroll
                for (int i = 0; i < 4; ++i)
                    a[i] = *(const short8*)&s_in[((mw * 4 + i + dy) * 18 + m + dx) * 40 + q * 8];
                #pragma unroll
                for (int i = 0; i < 4; ++i)
                    #pragma unroll
                    for (int j = 0; j < 2; ++j)
                        acc[i][j] = __builtin_amdgcn_mfma_f32_16x16x32_bf16(
                            a[i], bf[j], acc[i][j], 0, 0, 0);
            }
        }
    }
    float betav = (MODE == 1) ? beta[0] : 0.0f;
    #pragma unroll
    for (int j = 0; j < 2; ++j) {
        int o = nw * 32 + j * 16 + m;
        float cbf = cb[o];
        float scale = 1.0f, shift = 0.0f;
        if (MODE == 0) {
            float g  = bnp[o],       bt = bnp[64 + o];
            float mm = bnp[128 + o], vv = bnp[192 + o];
            scale = g * rsqrtf(vv + 1e-5f);
            shift = bt - mm * scale;
        }
        #pragma unroll
        for (int i = 0; i < 4; ++i) {
            int y = ty0 + mw * 4 + i;
            int base = ((b * 64 + o) << 14) + (y << 7) + tx0 + q * 4;
            float vals[4];
            if (MODE == 1) {
                short4v dv = *(const short4v*)&dep[base];
                #pragma unroll
                for (int reg = 0; reg < 4; ++reg)
                    vals[reg] = bfb2f(dv[reg]) + betav * (acc[i][j][reg] + cbf);
            } else {
                #pragma unroll
                for (int reg = 0; reg < 4; ++reg)
                    vals[reg] = fmaxf((acc[i][j][reg] + cbf) * scale + shift, 0.0f);
            }
            if (OUTBF) {
                short4v sv;
                #pragma unroll
                for (int reg = 0; reg < 4; ++reg) sv[reg] = f2bf_s(vals[reg]);
                *(short4v*)((short*)out + base) = sv;
            } else {
                f32x4 fv;
                #pragma unroll
                for (int reg = 0; reg < 4; ++reg) fv[reg] = vals[reg];
                *(f32x4*)((float*)out + base) = fv;
            }
        }
    }
}

// ---------------- final 7x7 conv (64->1): scalar-global weights + ILP-4 ----------------
__global__ __launch_bounds__(256) void k_outconv(
    const float* __restrict__ r,
    const float* __restrict__ w,
    const float* __restrict__ ob,
    float* __restrict__ out) {
    __shared__ float s_in[8][22][22];
    int tid = threadIdx.x;
    int ty = tid >> 4, tx = tid & 15;
    int ty0 = (blockIdx.x >> 3) << 4, tx0 = (blockIdx.x & 7) << 4;
    int b = blockIdx.z;
    float acc4[4] = {0.f, 0.f, 0.f, 0.f};
    for (int c0 = 0; c0 < 64; c0 += 8) {
        __syncthreads();
        for (int e = tid; e < 8 * 484; e += 256) {
            int i = e / 484; int r2 = e - i * 484; int yy = r2 / 22; int xx = r2 - yy * 22;
            int gy = ty0 + yy - 3, gx = tx0 + xx - 3;
            float v = 0.0f;
            if ((unsigned)gy < 128u && (unsigned)gx < 128u)
                v = r[((b * 64 + c0 + i) << 14) + (gy << 7) + gx];
            s_in[i][yy][xx] = v;
        }
        __syncthreads();
        for (int i = 0; i < 8; ++i) {
            const float* wrow = w + (c0 + i) * 49;   // wave-uniform -> scalar loads
            #pragma unroll
            for (int dy = 0; dy < 7; ++dy)
                #pragma unroll
                for (int dx = 0; dx < 7; ++dx)
                    acc4[i & 3] = fmaf(s_in[i][ty + dy][tx + dx], wrow[dy * 7 + dx], acc4[i & 3]);
        }
    }
    out[(b << 14) + ((ty0 + ty) << 7) + tx0 + tx] =
        (acc4[0] + acc4[1]) + (acc4[2] + acc4[3]) + ob[0];
}

extern "C" void kernel_launch(void* const* d_in, const int* in_sizes, int n_in,
                              void* d_out, int out_size, void* d_ws, size_t ws_size,
                              hipStream_t stream) {
    const float* cur_x  = (const float*)d_in[0];
    const float* dep_x  = (const float*)d_in[1];
    const float* in_map = (const float*)d_in[2];
    const float* up_w   = (const float*)d_in[3];
    const float* up_b   = (const float*)d_in[4];
    const float* up_bn  = (const float*)d_in[5];
    const float* c2_w   = (const float*)d_in[6];
    const float* c2_b   = (const float*)d_in[7];
    const float* d1_w   = (const float*)d_in[8];
    const float* d1_b   = (const float*)d_in[9];
    const float* d1_bn  = (const float*)d_in[10];
    const float* d2_w   = (const float*)d_in[11];
    const float* d2_b   = (const float*)d_in[12];
    const float* d2_bn  = (const float*)d_in[13];
    const float* d3_w   = (const float*)d_in[14];
    const float* d3_b   = (const float*)d_in[15];
    const float* d3_bn  = (const float*)d_in[16];
    const float* out_w  = (const float*)d_in[17];
    const float* out_b  = (const float*)d_in[18];
    const float* beta   = (const float*)d_in[19];

    // Buffer plan (ws use = 16.8 MiB, proven safe):
    //   A  = ws[0..16.8M) bf16      : xin2 (steps 2-6) then r2 (steps 8-9)
    //   B  = d_out[0..16.8M) bf16   : dep (5-6) then r1 (7-8)
    //   C  = d_out[16.8..33.5M) bf16: wb at head (4-5) then t (6-7)
    //   map region d_out[33.5..34M) : om_bf (1-2) -> wb3 (3-9) -> final map (10)
    //   r_out fp32 = d_out[0..33.5M): final r written by d3 (step 9)
    char* ob = (char*)d_out;
    float* r_out  = (float*)ob;
    short* A      = (short*)d_ws;
    short* B      = (short*)ob;
    short* C      = (short*)(ob + 16777216);
    short* wb     = C;
    short* om_bf  = (short*)(ob + 33554432);
    short* wb3    = (short*)(ob + 33554432);
    float* mapout = (float*)(ob + 33554432);

    k_maps<<<dim3(64, 1, 8), 256, 0, stream>>>(in_map, om_bf);
    k_premult<<<8192, 256, 0, stream>>>(cur_x, om_bf, A);
    k_prepw3<<<576, 256, 0, stream>>>(c2_w, d1_w, d2_w, d3_w, wb3);
    k_prepw<<<6272, 256, 0, stream>>>(up_w, wb);
    k_upconv_mfma<<<dim3(16, 4, 8), 512, 0, stream>>>(dep_x, wb, up_b, up_bn, B);
    k_conv3m<1, true><<<dim3(128, 1, 8), 256, 0, stream>>>(
        A, wb3 + 0 * 36864, B, c2_b, nullptr, beta, C);
    k_conv3m<0, true><<<dim3(128, 1, 8), 256, 0, stream>>>(
        C, wb3 + 1 * 36864, nullptr, d1_b, d1_bn, nullptr, B);
    k_conv3m<0, true><<<dim3(128, 1, 8), 256, 0, stream>>>(
        B, wb3 + 2 * 36864, nullptr, d2_b, d2_bn, nullptr, A);
    k_conv3m<0, false><<<dim3(128, 1, 8), 256, 0, stream>>>(
        A, wb3 + 3 * 36864, nullptr, d3_b, d3_bn, nullptr, r_out);
    k_outconv<<<dim3(64, 1, 8), 256, 0, stream>>>(r_out, out_w, out_b, mapout);
}